// Round 13
// baseline (245.785 us; speedup 1.0000x reference)
//
#include <hip/hip_runtime.h>
#include <stdint.h>

#define D_DIM 4096
#define N_ROWS 8192

typedef __attribute__((ext_vector_type(8))) short bfrag8;
typedef __attribute__((ext_vector_type(4))) float facc4;
typedef unsigned long long u64;

union ABfrag { uint32_t u[4]; bfrag8 b; };

__device__ __forceinline__ uint32_t pack_bf16x2(float lo, float hi) {
    union { float f; uint32_t u; } a, b;
    a.f = lo; b.f = hi;
    return (b.u & 0xFFFF0000u) | (a.u >> 16);   // truncate-to-bf16
}

// ---------------------------------------------------------------------------
// Kernel 0: A fp32 -> bf16, XOR-swizzled per-K-chunk image (verified).
// ---------------------------------------------------------------------------
__global__ void __launch_bounds__(256)
prep_A(const float* __restrict__ A, uint32_t* __restrict__ A_sw) {
    const int S = blockIdx.x * 256 + threadIdx.x;  // 0..65535
    const int c = S >> 10;
    const int s = S & 1023;
    const int n = s >> 3;
    const int g = (s & 7) ^ (n & 7);
    const float* src = A + (size_t)n * D_DIM + c * 64 + g * 8;
    float4 f0 = *(const float4*)(src);
    float4 f1 = *(const float4*)(src + 4);
    uint4 o;
    o.x = pack_bf16x2(f0.x, f0.y);
    o.y = pack_bf16x2(f0.z, f0.w);
    o.z = pack_bf16x2(f1.x, f1.y);
    o.w = pack_bf16x2(f1.z, f1.w);
    *(uint4*)(A_sw + (size_t)S * 4) = o;
}

// ---------------------------------------------------------------------------
// Kernel 1: GEMM, 1-WAVE BLOCKS, zero LDS, zero barriers, split-K partials.
// Grid (S, 512), 64 threads. Wave = 16 rows x 128 cols x K=4096/S.
// Theory (R11 counters): all prior structures were latency-bound at
// ~1.2 TB/s effective read BW because per-wave MLP was ~2 loads (compiler
// sank staged loads; VGPR=56) and blocks/CU was capped. Fix = TLP:
// 4096 independent waves, 16/CU at VGPR<=128; per chunk all 20 loads are
// independent (4 L float4 + 16 B 16B from the verified swizzled image),
// consumed in-chunk (no prefetch ring for the compiler to collapse).
// Output: fp32 partials in the R0-verified layout -> reduce_pack.
// B address math == verified ds_read path (audited R6): uint32 offset
// n*32 + (gl^(n&7))*4, n=16ct+c folded as ct*512 + c*32 + sw.
// C/D layout (R0/m89-verified): out_row = 4q+r, out_col = 16ct+c.
// (Resubmission: round-12 bench was a GPU-acquisition timeout, kernel unrun.)
// ---------------------------------------------------------------------------
__global__ void __launch_bounds__(64, 4)
gemm_wave(const float* __restrict__ L, const uint32_t* __restrict__ A_sw,
          float* __restrict__ partials, int nchunk) {
    const int lane  = threadIdx.x;   // 0..63
    const int split = blockIdx.x;
    const int row0  = blockIdx.y * 16;
    const int c = lane & 15;         // L row within tile / B column low bits
    const int q = lane >> 4;         // k-octet select

    const int kc0 = split * nchunk;  // K offset in 64-elem chunks
    const float* Lrow = L + (size_t)(row0 + c) * D_DIM + (size_t)kc0 * 64 + q * 8;
    const uint32_t* gB0 = A_sw + (size_t)kc0 * 4096 + c * 32;
    const int sw0 = (q ^ (c & 7)) * 4;        // gl = q   (ks=0), uint32 units
    const int sw1 = ((4 + q) ^ (c & 7)) * 4;  // gl = 4+q (ks=1)

    facc4 acc[8];
#pragma unroll
    for (int i = 0; i < 8; i++) acc[i] = (facc4){0.f, 0.f, 0.f, 0.f};

#pragma unroll 2
    for (int t = 0; t < nchunk; t++) {
        const float* p = Lrow + t * 64;
        // 4 independent 16B loads covering this lane's 32 fp32 of the chunk.
        float4 f0 = *(const float4*)(p);        // ks=0, k = q*8..q*8+3
        float4 f1 = *(const float4*)(p + 4);    // ks=0, k = q*8+4..q*8+7
        float4 f2 = *(const float4*)(p + 32);   // ks=1
        float4 f3 = *(const float4*)(p + 36);   // ks=1

        ABfrag a0, a1;
        a0.u[0] = pack_bf16x2(f0.x, f0.y);
        a0.u[1] = pack_bf16x2(f0.z, f0.w);
        a0.u[2] = pack_bf16x2(f1.x, f1.y);
        a0.u[3] = pack_bf16x2(f1.z, f1.w);
        a1.u[0] = pack_bf16x2(f2.x, f2.y);
        a1.u[1] = pack_bf16x2(f2.z, f2.w);
        a1.u[2] = pack_bf16x2(f3.x, f3.y);
        a1.u[3] = pack_bf16x2(f3.z, f3.w);

        const uint32_t* gB = gB0 + (size_t)t * 4096;
#pragma unroll
        for (int ct = 0; ct < 8; ct++) {
            bfrag8 b0 = *(const bfrag8*)(gB + ct * 512 + sw0);
            acc[ct] = __builtin_amdgcn_mfma_f32_16x16x32_bf16(a0.b, b0, acc[ct], 0, 0, 0);
        }
#pragma unroll
        for (int ct = 0; ct < 8; ct++) {
            bfrag8 b1 = *(const bfrag8*)(gB + ct * 512 + sw1);
            acc[ct] = __builtin_amdgcn_mfma_f32_16x16x32_bf16(a1.b, b1, acc[ct], 0, 0, 0);
        }
    }

    // fp32 partial tile (verified layout): P[split][row0+4q+r][16ct+c].
    float* P = partials + (size_t)split * N_ROWS * 128 + (size_t)row0 * 128;
#pragma unroll
    for (int ct = 0; ct < 8; ct++)
#pragma unroll
        for (int r = 0; r < 4; r++)
            P[(size_t)(4 * q + r) * 128 + 16 * ct + c] = acc[ct][r];
}

// ---------------------------------------------------------------------------
// Kernel 1b: reduce S partials, sign -> 128-bit key -> 64-bit fold
// (R0-verified, unchanged).
// ---------------------------------------------------------------------------
__global__ void __launch_bounds__(256)
reduce_pack(const float* __restrict__ partials, u64* __restrict__ folded, int S) {
    const int row  = blockIdx.x * 4 + (threadIdx.x >> 6);
    const int lane = threadIdx.x & 63;
    float s0 = 0.f, s1 = 0.f;
    for (int s = 0; s < S; s++) {
        const float* P = partials + ((size_t)s * N_ROWS * 128) + (size_t)row * 128;
        s0 += P[lane];
        s1 += P[lane + 64];
    }
    u64 b0 = __ballot(s0 > 0.0f);
    u64 b1 = __ballot(s1 > 0.0f);
    if (lane == 0) folded[row] = b0 ^ b1;
}

// ---------------------------------------------------------------------------
// Kernel 2: ordered duplicate count, LDS-staged keys, load-balanced rows
// (verified, unchanged).
// ---------------------------------------------------------------------------
__global__ void __launch_bounds__(512)
count_rows(const u64* __restrict__ folded, float* __restrict__ out) {
    __shared__ u64 K[N_ROWS];
    const int tid = threadIdx.x;
    for (int i = tid; i < N_ROWS; i += 512) K[i] = folded[i];
    __syncthreads();

    const int g    = blockIdx.x * 8 + (tid >> 6);   // 0..2047
    const int lane = tid & 63;
    int rows[4];
    u64 my[4];
    int cnt[4] = {0, 0, 0, 0};
#pragma unroll
    for (int r = 0; r < 4; r++) {
        rows[r] = g + 2048 * r;
        my[r] = K[rows[r]];
    }
    const int maxrow = rows[3];
    for (int j = lane; j <= maxrow; j += 64) {
        u64 k = K[j];
#pragma unroll
        for (int r = 0; r < 4; r++)
            cnt[r] += (int)((j <= rows[r]) & (k == my[r]));
    }
#pragma unroll
    for (int r = 0; r < 4; r++) {
        int v = cnt[r];
#pragma unroll
        for (int o = 32; o; o >>= 1) v += __shfl_xor(v, o, 64);
        if (lane == 0) out[rows[r]] = rsqrtf((float)v);
    }
}

extern "C" void kernel_launch(void* const* d_in, const int* in_sizes, int n_in,
                              void* d_out, int out_size, void* d_ws, size_t ws_size,
                              hipStream_t stream) {
    const float* latent = (const float*)d_in[0];   // [128,64,4096] fp32
    const float* A      = (const float*)d_in[1];   // [128,4096] fp32
    float* out          = (float*)d_out;           // [8192] fp32

    uint32_t* A_sw = (uint32_t*)d_ws;                                   // 1 MB
    u64* folded = (u64*)((char*)d_ws + (1 << 20));                      // 64 KB
    float* partials = (float*)((char*)d_ws + (1 << 20) + (1 << 16));    // S * 4 MB

    const size_t base = (1 << 20) + (1 << 16);
    const size_t per_split = (size_t)N_ROWS * 128 * sizeof(float);      // 4 MB
    int S = 1;
    if (ws_size >= base + 8 * per_split)      S = 8;
    else if (ws_size >= base + 4 * per_split) S = 4;
    else if (ws_size >= base + 2 * per_split) S = 2;

    prep_A<<<256, 256, 0, stream>>>(A, A_sw);
    gemm_wave<<<dim3(S, 512), 64, 0, stream>>>(latent, A_sw, partials, 64 / S);
    reduce_pack<<<2048, 256, 0, stream>>>(partials, folded, S);
    count_rows<<<256, 512, 0, stream>>>(folded, out);
}

// Round 14
// 223.827 us; speedup vs baseline: 1.0981x; 1.0981x over previous
//
#include <hip/hip_runtime.h>
#include <stdint.h>

#define D_DIM 4096
#define N_ROWS 8192

typedef __attribute__((ext_vector_type(8))) short bfrag8;
typedef __attribute__((ext_vector_type(4))) float facc4;
typedef unsigned long long u64;

union ABfrag { uint32_t u[4]; bfrag8 b; };

__device__ __forceinline__ uint32_t pack_bf16x2(float lo, float hi) {
    union { float f; uint32_t u; } a, b;
    a.f = lo; b.f = hi;
    return (b.u & 0xFFFF0000u) | (a.u >> 16);   // truncate-to-bf16
}

// ---------------------------------------------------------------------------
// Kernel 0: A fp32 -> bf16, XOR-swizzled per-K-chunk image (verified).
// ---------------------------------------------------------------------------
__global__ void __launch_bounds__(256)
prep_A(const float* __restrict__ A, uint32_t* __restrict__ A_sw) {
    const int S = blockIdx.x * 256 + threadIdx.x;  // 0..65535
    const int c = S >> 10;
    const int s = S & 1023;
    const int n = s >> 3;
    const int g = (s & 7) ^ (n & 7);
    const float* src = A + (size_t)n * D_DIM + c * 64 + g * 8;
    float4 f0 = *(const float4*)(src);
    float4 f1 = *(const float4*)(src + 4);
    uint4 o;
    o.x = pack_bf16x2(f0.x, f0.y);
    o.y = pack_bf16x2(f0.z, f0.w);
    o.z = pack_bf16x2(f1.x, f1.y);
    o.w = pack_bf16x2(f1.z, f1.w);
    *(uint4*)(A_sw + (size_t)S * 4) = o;
}

// ---------------------------------------------------------------------------
// Kernel 1: split-K GEMM, BM=128, ALL staging via global_load_lds.
// Theory (R10/R11/R13 counters): reg-staged loads get sunk by the compiler
// (VGPR 28-64) into load->wait chains -> 1.2 TB/s latency-bound. Fix: L is
// staged as RAW FP32 via global_load_lds (no reg result -> cannot be sunk;
// 48 KB in flight per block), packed to bf16 AFTER ds_read.
// Swizzle (both-sides rule): LDS slot j of row r holds L[r][j ^ (r&7)]
// (16B units); write side: per-lane source j_src = (lane&15) ^ (r&7);
// read side: a-frag at 16B-index j0 = ks*8+q*2 reads slot j0 ^ (c&7)
// -> 8-bank spread, 2-way conflict (free). B path bit-identical to R11.
// Grid (8, 64), 256 thr, LDS 48 KB, 2 blocks/CU. Partials -> reduce_pack.
// ---------------------------------------------------------------------------
__global__ void __launch_bounds__(256, 2)
gemm_split128(const float* __restrict__ L, const uint32_t* __restrict__ A_sw,
              float* __restrict__ partials, int kpb) {
    __shared__ uint32_t Lf[8192];     // 32 KB: 128 rows x 16 slots x 16B (fp32)
    __shared__ uint4    As[1024];     // 16 KB: B chunk (verified swizzled image)

    const int tid  = threadIdx.x;
    const int wave = tid >> 6;
    const int lane = tid & 63;
    const int split = blockIdx.x;
    const int row0 = blockIdx.y * 128;
    const int c  = lane & 15;
    const int q  = lane >> 4;
    const int wm = wave >> 1;         // 64-row half
    const int wn = wave & 1;          // 64-col half

    // L-staging geometry (wave-uniform dst, per-lane swizzled src).
    // call i: rows i*16 + wave*4 + (lane>>4); r&7 = (wave*4+(lane>>4))&7.
    const int lrow_lo = wave * 4 + (lane >> 4);          // row low bits, 0..15
    const int js      = (lane & 15) ^ (lrow_lo & 7);     // src 16B-slot in row
    const float* lsrc0 = L + (size_t)(row0 + lrow_lo) * D_DIM + js * 4;

    facc4 acc[4][4];
#pragma unroll
    for (int m = 0; m < 4; m++)
#pragma unroll
        for (int ct = 0; ct < 4; ct++) acc[m][ct] = (facc4){0.f, 0.f, 0.f, 0.f};

    const int kc0 = split * kpb * 64;
    const int kc1 = kc0 + kpb * 64;
    for (int kc = kc0; kc < kc1; kc += 64) {
        // B: 16 KB via 4 global_load_lds per wave (R11-verified path).
        const uint32_t* gA = A_sw + (size_t)(kc >> 6) * 4096;
#pragma unroll
        for (int i = 0; i < 4; i++) {
            const int slot0 = wave * 256 + i * 64;
            __builtin_amdgcn_global_load_lds(
                (const __attribute__((address_space(1))) uint32_t*)(gA + (slot0 + lane) * 4),
                (__attribute__((address_space(3))) uint32_t*)(&As[slot0]),
                16, 0, 0);
        }
        // L: 32 KB raw fp32 via 8 global_load_lds per wave, source-swizzled.
#pragma unroll
        for (int i = 0; i < 8; i++) {
            const uint32_t* src = (const uint32_t*)(lsrc0 + (size_t)(i * 16) * D_DIM + kc);
            __builtin_amdgcn_global_load_lds(
                (const __attribute__((address_space(1))) uint32_t*)src,
                (__attribute__((address_space(3))) uint32_t*)(&Lf[(i * 256 + wave * 64) * 4]),
                16, 0, 0);
        }
        __syncthreads();

#pragma unroll
        for (int ks = 0; ks < 2; ks++) {
            // a-frags: 2x ds_read_b128 fp32 (swizzled slots) + 4 packs each.
            ABfrag a[4];
#pragma unroll
            for (int m = 0; m < 4; m++) {
                const int rr = 64 * wm + 16 * m + c;        // rr&7 == c&7
                const int j0 = ks * 8 + q * 2;
                const float4 f0 = *(const float4*)&Lf[rr * 64 + ((j0    ) ^ (c & 7)) * 4];
                const float4 f1 = *(const float4*)&Lf[rr * 64 + ((j0 + 1) ^ (c & 7)) * 4];
                a[m].u[0] = pack_bf16x2(f0.x, f0.y);
                a[m].u[1] = pack_bf16x2(f0.z, f0.w);
                a[m].u[2] = pack_bf16x2(f1.x, f1.y);
                a[m].u[3] = pack_bf16x2(f1.z, f1.w);
            }
#pragma unroll
            for (int ct = 0; ct < 4; ct++) {
                const int n  = 64 * wn + 16 * ct + c;
                const int gl = ks * 4 + q;
                bfrag8 b = *(const bfrag8*)&As[n * 8 + (gl ^ (n & 7))];
#pragma unroll
                for (int m = 0; m < 4; m++)
                    acc[m][ct] = __builtin_amdgcn_mfma_f32_16x16x32_bf16(a[m].b, b, acc[m][ct], 0, 0, 0);
            }
        }
        __syncthreads();
    }

    // C/D layout (verified): row = 4q + r within tile, col = c.
    float* P = partials + ((size_t)split * N_ROWS * 128);
    const int cb = 64 * wn + c;
#pragma unroll
    for (int m = 0; m < 4; m++) {
        const int rb = row0 + 64 * wm + 16 * m + 4 * q;
#pragma unroll
        for (int ct = 0; ct < 4; ct++)
#pragma unroll
            for (int r = 0; r < 4; r++)
                P[(size_t)(rb + r) * 128 + cb + 16 * ct] = acc[m][ct][r];
    }
}

// ---------------------------------------------------------------------------
// Kernel 1b: reduce S partials, sign -> 128-bit key -> 64-bit fold
// (R0-verified, unchanged).
// ---------------------------------------------------------------------------
__global__ void __launch_bounds__(256)
reduce_pack(const float* __restrict__ partials, u64* __restrict__ folded, int S) {
    const int row  = blockIdx.x * 4 + (threadIdx.x >> 6);
    const int lane = threadIdx.x & 63;
    float s0 = 0.f, s1 = 0.f;
    for (int s = 0; s < S; s++) {
        const float* P = partials + ((size_t)s * N_ROWS * 128) + (size_t)row * 128;
        s0 += P[lane];
        s1 += P[lane + 64];
    }
    u64 b0 = __ballot(s0 > 0.0f);
    u64 b1 = __ballot(s1 > 0.0f);
    if (lane == 0) folded[row] = b0 ^ b1;
}

// ---------------------------------------------------------------------------
// Kernel 2: ordered duplicate count, LDS-staged keys, load-balanced rows
// (verified, unchanged).
// ---------------------------------------------------------------------------
__global__ void __launch_bounds__(512)
count_rows(const u64* __restrict__ folded, float* __restrict__ out) {
    __shared__ u64 K[N_ROWS];
    const int tid = threadIdx.x;
    for (int i = tid; i < N_ROWS; i += 512) K[i] = folded[i];
    __syncthreads();

    const int g    = blockIdx.x * 8 + (tid >> 6);   // 0..2047
    const int lane = tid & 63;
    int rows[4];
    u64 my[4];
    int cnt[4] = {0, 0, 0, 0};
#pragma unroll
    for (int r = 0; r < 4; r++) {
        rows[r] = g + 2048 * r;
        my[r] = K[rows[r]];
    }
    const int maxrow = rows[3];
    for (int j = lane; j <= maxrow; j += 64) {
        u64 k = K[j];
#pragma unroll
        for (int r = 0; r < 4; r++)
            cnt[r] += (int)((j <= rows[r]) & (k == my[r]));
    }
#pragma unroll
    for (int r = 0; r < 4; r++) {
        int v = cnt[r];
#pragma unroll
        for (int o = 32; o; o >>= 1) v += __shfl_xor(v, o, 64);
        if (lane == 0) out[rows[r]] = rsqrtf((float)v);
    }
}

extern "C" void kernel_launch(void* const* d_in, const int* in_sizes, int n_in,
                              void* d_out, int out_size, void* d_ws, size_t ws_size,
                              hipStream_t stream) {
    const float* latent = (const float*)d_in[0];   // [128,64,4096] fp32
    const float* A      = (const float*)d_in[1];   // [128,4096] fp32
    float* out          = (float*)d_out;           // [8192] fp32

    uint32_t* A_sw = (uint32_t*)d_ws;                                   // 1 MB
    u64* folded = (u64*)((char*)d_ws + (1 << 20));                      // 64 KB
    float* partials = (float*)((char*)d_ws + (1 << 20) + (1 << 16));    // S * 4 MB

    const size_t base = (1 << 20) + (1 << 16);
    const size_t per_split = (size_t)N_ROWS * 128 * sizeof(float);      // 4 MB
    int S = 1;
    if (ws_size >= base + 8 * per_split)      S = 8;
    else if (ws_size >= base + 4 * per_split) S = 4;
    else if (ws_size >= base + 2 * per_split) S = 2;

    prep_A<<<256, 256, 0, stream>>>(A, A_sw);
    gemm_split128<<<dim3(S, 64), 256, 0, stream>>>(latent, A_sw, partials, 64 / S);
    reduce_pack<<<2048, 256, 0, stream>>>(partials, folded, S);
    count_rows<<<256, 512, 0, stream>>>(folded, out);
}

// Round 17
// 223.402 us; speedup vs baseline: 1.1002x; 1.0019x over previous
//
#include <hip/hip_runtime.h>
#include <stdint.h>

#define D_DIM 4096
#define N_ROWS 8192

typedef __attribute__((ext_vector_type(8))) short bfrag8;
typedef __attribute__((ext_vector_type(4))) float facc4;
typedef unsigned long long u64;

union ABfrag { uint32_t u[4]; bfrag8 b; };

__device__ __forceinline__ uint32_t pack_bf16x2(float lo, float hi) {
    union { float f; uint32_t u; } a, b;
    a.f = lo; b.f = hi;
    return (b.u & 0xFFFF0000u) | (a.u >> 16);   // truncate-to-bf16
}

// ---------------------------------------------------------------------------
// Kernel 0: A fp32 -> bf16, XOR-swizzled per-K-chunk image (verified).
// ---------------------------------------------------------------------------
__global__ void __launch_bounds__(256)
prep_A(const float* __restrict__ A, uint32_t* __restrict__ A_sw) {
    const int S = blockIdx.x * 256 + threadIdx.x;  // 0..65535
    const int c = S >> 10;
    const int s = S & 1023;
    const int n = s >> 3;
    const int g = (s & 7) ^ (n & 7);
    const float* src = A + (size_t)n * D_DIM + c * 64 + g * 8;
    float4 f0 = *(const float4*)(src);
    float4 f1 = *(const float4*)(src + 4);
    uint4 o;
    o.x = pack_bf16x2(f0.x, f0.y);
    o.y = pack_bf16x2(f0.z, f0.w);
    o.z = pack_bf16x2(f1.x, f1.y);
    o.w = pack_bf16x2(f1.z, f1.w);
    *(uint4*)(A_sw + (size_t)S * 4) = o;
}

// ---------------------------------------------------------------------------
// Kernel 1: split-K GEMM, BM=64, all staging via global_load_lds.
// R14 (BM=128, 512 blocks = 2/CU) proved gload_lds staging fixes the
// load-sinking disease (gemm 81.8 -> <77, best end-to-end). Remaining ~2x
// over the bytes floor = the per-K-step vmcnt(0)+barrier drain, which m97/
// m114 shows is covered by CO-RESIDENT INDEPENDENT BLOCKS (needs >=3/CU;
// we had exactly 2, dispatched in phase). This round: BM 128->64 ->
// grid (8,128) = 1024 blocks = 4 blocks/CU (LDS 32 KB, VGPR ~halved),
// 16 waves/CU of independent work to cover each other's drains.
// K-loop body / swizzles / layouts are the R14-verified code with the
// m-extent halved (acc[2][4], 2 row-groups). Pure occupancy change.
// Swizzle (both-sides rule, R14-verified): LDS 16B-slot j of row r holds
// L[r][j ^ (r&7)]; write src j_src=(lane&15)^(r&7); read j0^(c&7).
// (Resubmission x2: rounds 15-16 were GPU-acquisition timeouts, unrun.)
// ---------------------------------------------------------------------------
__global__ void __launch_bounds__(256, 2)
gemm_split64(const float* __restrict__ L, const uint32_t* __restrict__ A_sw,
             float* __restrict__ partials, int kpb) {
    __shared__ uint32_t Lf[4096];     // 16 KB: 64 rows x 16 slots x 16B (fp32)
    __shared__ uint4    As[1024];     // 16 KB: B chunk (verified swizzled image)

    const int tid  = threadIdx.x;
    const int wave = tid >> 6;
    const int lane = tid & 63;
    const int split = blockIdx.x;
    const int row0 = blockIdx.y * 64;
    const int c  = lane & 15;
    const int q  = lane >> 4;
    const int wm = wave >> 1;         // 32-row half
    const int wn = wave & 1;          // 64-col half

    // L-staging geometry (wave-uniform dst, per-lane swizzled src).
    // call i: row = i*16 + wave*4 + (lane>>4); dst = linear lane*16B.
    const int lrow_lo = wave * 4 + (lane >> 4);          // 0..15
    const int js      = (lane & 15) ^ (lrow_lo & 7);     // src 16B-slot in row
    const float* lsrc0 = L + (size_t)(row0 + lrow_lo) * D_DIM + js * 4;

    facc4 acc[2][4];
#pragma unroll
    for (int m = 0; m < 2; m++)
#pragma unroll
        for (int ct = 0; ct < 4; ct++) acc[m][ct] = (facc4){0.f, 0.f, 0.f, 0.f};

    const int kc0 = split * kpb * 64;
    const int kc1 = kc0 + kpb * 64;
    for (int kc = kc0; kc < kc1; kc += 64) {
        // B: 16 KB via 4 global_load_lds per wave (verified path).
        const uint32_t* gA = A_sw + (size_t)(kc >> 6) * 4096;
#pragma unroll
        for (int i = 0; i < 4; i++) {
            const int slot0 = wave * 256 + i * 64;
            __builtin_amdgcn_global_load_lds(
                (const __attribute__((address_space(1))) uint32_t*)(gA + (slot0 + lane) * 4),
                (__attribute__((address_space(3))) uint32_t*)(&As[slot0]),
                16, 0, 0);
        }
        // L: 16 KB raw fp32 via 4 global_load_lds per wave, source-swizzled.
#pragma unroll
        for (int i = 0; i < 4; i++) {
            const uint32_t* src = (const uint32_t*)(lsrc0 + (size_t)(i * 16) * D_DIM + kc);
            __builtin_amdgcn_global_load_lds(
                (const __attribute__((address_space(1))) uint32_t*)src,
                (__attribute__((address_space(3))) uint32_t*)(&Lf[(i * 256 + wave * 64) * 4]),
                16, 0, 0);
        }
        __syncthreads();

#pragma unroll
        for (int ks = 0; ks < 2; ks++) {
            // a-frags: 2x ds_read_b128 fp32 (swizzled slots) + 4 packs each.
            ABfrag a[2];
#pragma unroll
            for (int m = 0; m < 2; m++) {
                const int rr = 32 * wm + 16 * m + c;        // rr&7 == c&7
                const int j0 = ks * 8 + q * 2;
                const float4 f0 = *(const float4*)&Lf[rr * 64 + ((j0    ) ^ (c & 7)) * 4];
                const float4 f1 = *(const float4*)&Lf[rr * 64 + ((j0 + 1) ^ (c & 7)) * 4];
                a[m].u[0] = pack_bf16x2(f0.x, f0.y);
                a[m].u[1] = pack_bf16x2(f0.z, f0.w);
                a[m].u[2] = pack_bf16x2(f1.x, f1.y);
                a[m].u[3] = pack_bf16x2(f1.z, f1.w);
            }
#pragma unroll
            for (int ct = 0; ct < 4; ct++) {
                const int n  = 64 * wn + 16 * ct + c;
                const int gl = ks * 4 + q;
                bfrag8 b = *(const bfrag8*)&As[n * 8 + (gl ^ (n & 7))];
#pragma unroll
                for (int m = 0; m < 2; m++)
                    acc[m][ct] = __builtin_amdgcn_mfma_f32_16x16x32_bf16(a[m].b, b, acc[m][ct], 0, 0, 0);
            }
        }
        __syncthreads();
    }

    // C/D layout (verified): row = 4q + r within tile, col = c.
    float* P = partials + ((size_t)split * N_ROWS * 128);
    const int cb = 64 * wn + c;
#pragma unroll
    for (int m = 0; m < 2; m++) {
        const int rb = row0 + 32 * wm + 16 * m + 4 * q;
#pragma unroll
        for (int ct = 0; ct < 4; ct++)
#pragma unroll
            for (int r = 0; r < 4; r++)
                P[(size_t)(rb + r) * 128 + cb + 16 * ct] = acc[m][ct][r];
    }
}

// ---------------------------------------------------------------------------
// Kernel 1b: reduce S partials, sign -> 128-bit key -> 64-bit fold
// (R0-verified, unchanged).
// ---------------------------------------------------------------------------
__global__ void __launch_bounds__(256)
reduce_pack(const float* __restrict__ partials, u64* __restrict__ folded, int S) {
    const int row  = blockIdx.x * 4 + (threadIdx.x >> 6);
    const int lane = threadIdx.x & 63;
    float s0 = 0.f, s1 = 0.f;
    for (int s = 0; s < S; s++) {
        const float* P = partials + ((size_t)s * N_ROWS * 128) + (size_t)row * 128;
        s0 += P[lane];
        s1 += P[lane + 64];
    }
    u64 b0 = __ballot(s0 > 0.0f);
    u64 b1 = __ballot(s1 > 0.0f);
    if (lane == 0) folded[row] = b0 ^ b1;
}

// ---------------------------------------------------------------------------
// Kernel 2: ordered duplicate count, LDS-staged keys, load-balanced rows
// (verified, unchanged).
// ---------------------------------------------------------------------------
__global__ void __launch_bounds__(512)
count_rows(const u64* __restrict__ folded, float* __restrict__ out) {
    __shared__ u64 K[N_ROWS];
    const int tid = threadIdx.x;
    for (int i = tid; i < N_ROWS; i += 512) K[i] = folded[i];
    __syncthreads();

    const int g    = blockIdx.x * 8 + (tid >> 6);   // 0..2047
    const int lane = tid & 63;
    int rows[4];
    u64 my[4];
    int cnt[4] = {0, 0, 0, 0};
#pragma unroll
    for (int r = 0; r < 4; r++) {
        rows[r] = g + 2048 * r;
        my[r] = K[rows[r]];
    }
    const int maxrow = rows[3];
    for (int j = lane; j <= maxrow; j += 64) {
        u64 k = K[j];
#pragma unroll
        for (int r = 0; r < 4; r++)
            cnt[r] += (int)((j <= rows[r]) & (k == my[r]));
    }
#pragma unroll
    for (int r = 0; r < 4; r++) {
        int v = cnt[r];
#pragma unroll
        for (int o = 32; o; o >>= 1) v += __shfl_xor(v, o, 64);
        if (lane == 0) out[rows[r]] = rsqrtf((float)v);
    }
}

extern "C" void kernel_launch(void* const* d_in, const int* in_sizes, int n_in,
                              void* d_out, int out_size, void* d_ws, size_t ws_size,
                              hipStream_t stream) {
    const float* latent = (const float*)d_in[0];   // [128,64,4096] fp32
    const float* A      = (const float*)d_in[1];   // [128,4096] fp32
    float* out          = (float*)d_out;           // [8192] fp32

    uint32_t* A_sw = (uint32_t*)d_ws;                                   // 1 MB
    u64* folded = (u64*)((char*)d_ws + (1 << 20));                      // 64 KB
    float* partials = (float*)((char*)d_ws + (1 << 20) + (1 << 16));    // S * 4 MB

    const size_t base = (1 << 20) + (1 << 16);
    const size_t per_split = (size_t)N_ROWS * 128 * sizeof(float);      // 4 MB
    int S = 1;
    if (ws_size >= base + 8 * per_split)      S = 8;
    else if (ws_size >= base + 4 * per_split) S = 4;
    else if (ws_size >= base + 2 * per_split) S = 2;

    prep_A<<<256, 256, 0, stream>>>(A, A_sw);
    gemm_split64<<<dim3(S, 128), 256, 0, stream>>>(latent, A_sw, partials, 64 / S);
    reduce_pack<<<2048, 256, 0, stream>>>(partials, folded, S);
    count_rows<<<256, 512, 0, stream>>>(folded, out);
}